// Round 1
// baseline (1229.390 us; speedup 1.0000x reference)
//
#include <hip/hip_runtime.h>
#include <cstdint>
#include <cstddef>

// ---------------- problem constants ----------------
#define TSTEPS 192
#define BATCH  4096
#define FRAW   20
#define FCONV  22
#define FCNN   11
#define HID    40
#define NOUT   21          // 1 gamma + 20 eta
#define ROWSPB 16          // rows per LSTM block
#define NTH    640         // 40 units * 16 rows

// ws layout: [0,1536) stats float2 per t ; feat at offset 4096
#define FEAT_OFF 4096

__device__ __forceinline__ float sigm_(float x){ return 1.f/(1.f+__expf(-x)); }
__device__ __forceinline__ float tanh_(float x){ float e=__expf(2.f*x); return 1.f-2.f/(e+1.f); }
__device__ __forceinline__ float softplus_(float x){ return fmaxf(x,0.f)+log1pf(__expf(-fabsf(x))); }

// -------- kernel 1: per-t BN affine params (deterministic block reduce) -----
__global__ __launch_bounds__(256)
void stats_kernel(const float* __restrict__ x_enc, const float* __restrict__ y_enc,
                  const float* __restrict__ conv_w, const float* __restrict__ conv_b,
                  const float* __restrict__ bn_w, const float* __restrict__ bn_b,
                  float* __restrict__ stats)
{
    const int t = blockIdx.x;
    const float w0=conv_w[0], w1=conv_w[1], w2=conv_w[2], cb=conv_b[0];
    const float* src = (t < 96) ? (x_enc + (size_t)t*21) : (y_enc + (size_t)(t-96)*21);
    float s=0.f, ss=0.f;
    for (int b = threadIdx.x; b < BATCH; b += 256) {
        const float* xr = src + (size_t)b*2016;   // 96*21
        float xv[FRAW];
        #pragma unroll
        for (int f=0; f<FRAW; ++f) xv[f] = xr[f];
        #pragma unroll
        for (int i=0; i<FCONV; ++i) {
            // circular pad by 2: xp[i] = x[(i+18)%20]
            float y = fmaf(w0, xv[(i+18)%20], fmaf(w1, xv[(i+19)%20], fmaf(w2, xv[i%20], cb)));
            s += y; ss = fmaf(y, y, ss);
        }
    }
    __shared__ float rs[256], rq[256];
    rs[threadIdx.x]=s; rq[threadIdx.x]=ss;
    __syncthreads();
    for (int o=128; o>0; o>>=1){
        if (threadIdx.x < o){ rs[threadIdx.x]+=rs[threadIdx.x+o]; rq[threadIdx.x]+=rq[threadIdx.x+o]; }
        __syncthreads();
    }
    if (threadIdx.x == 0){
        const float N = (float)(BATCH*FCONV);
        float mu  = rs[0]/N;
        float var = rq[0]/N - mu*mu;
        float A   = rsqrtf(var + 1e-5f) * bn_w[0];
        stats[2*t]   = A;
        stats[2*t+1] = bn_b[0] - mu*A;
    }
}

// -------- kernel 2: conv + BN + ELU + maxpool -> feat[t][b][11] -------------
__global__ __launch_bounds__(256)
void feat_kernel(const float* __restrict__ x_enc, const float* __restrict__ y_enc,
                 const float* __restrict__ conv_w, const float* __restrict__ conv_b,
                 const float* __restrict__ stats, float* __restrict__ feat)
{
    const int t = blockIdx.x;
    const int b = blockIdx.y*256 + threadIdx.x;
    const float w0=conv_w[0], w1=conv_w[1], w2=conv_w[2], cb=conv_b[0];
    const float A = stats[2*t], Bc = stats[2*t+1];
    const float* xr = ((t<96) ? (x_enc + (size_t)t*21) : (y_enc + (size_t)(t-96)*21)) + (size_t)b*2016;
    float xv[FRAW];
    #pragma unroll
    for (int f=0; f<FRAW; ++f) xv[f] = xr[f];
    float yv[FCONV];
    #pragma unroll
    for (int i=0; i<FCONV; ++i) {
        float y = fmaf(w0, xv[(i+18)%20], fmaf(w1, xv[(i+19)%20], fmaf(w2, xv[i%20], cb)));
        y = fmaf(y, A, Bc);                 // BN affine
        yv[i] = (y > 0.f) ? y : expm1f(y);  // ELU alpha=1
    }
    float* fo = feat + ((size_t)t*BATCH + b)*FCNN;
    #pragma unroll
    for (int i=0; i<FCNN; ++i) {
        float m = (i==0) ? fmaxf(yv[0], yv[1])
                         : fmaxf(yv[2*i-1], fmaxf(yv[2*i], yv[2*i+1]));
        fo[i] = m;
    }
}

// -------- kernel 3: persistent 2-layer LSTM + heads -------------------------
// 256 blocks x 640 threads. Block owns 16 rows for all 192 steps.
// thread = (j = tid>>4 in [0,40), r = tid&15 in [0,16)).
// LDS (dynamic, 102176 B):
//   W0  float4[51*40]  gate-interleaved cat(w_ih0,w_hh0) k-major
//   W1  float4[80*40]  cat(w_ih1,w_hh1)
//   Wh  float [80*22]  heads, hp-interleave pre-applied
//   bc0,bc1 float4[40]; bh float[22]
//   S0  float[16*53]   [0,11)=feat, [11,51)=h0   (stride 53, odd)
//   S1  float[16*81]   [0,40)=h0new, [40,80)=h1  (stride 81, odd)
//   Sout float[16*21]
#define SMEM_BYTES 102176

__global__ __launch_bounds__(NTH)
void lstm_kernel(const float* __restrict__ feat,
                 const float* __restrict__ w_ih0, const float* __restrict__ w_hh0, const float* __restrict__ b0,
                 const float* __restrict__ w_ih1, const float* __restrict__ w_hh1, const float* __restrict__ b1,
                 const float* __restrict__ w_gamma, const float* __restrict__ b_gamma,
                 const float* __restrict__ w_eta,   const float* __restrict__ b_eta,
                 float* __restrict__ out)
{
    extern __shared__ char smem[];
    float4* W0   = (float4*)(smem);              // 32640
    float4* W1   = (float4*)(smem + 32640);      // 51200
    float*  Wh   = (float*) (smem + 83840);      // 7040
    float4* bc0v = (float4*)(smem + 90880);      // 640
    float4* bc1v = (float4*)(smem + 91520);      // 640
    float*  bh   = (float*) (smem + 92160);      // 88 (+pad)
    float*  S0   = (float*) (smem + 92256);      // 3392
    float*  S1   = (float*) (smem + 95648);      // 5184
    float*  Sout = (float*) (smem + 100832);     // 1344

    const int tid = threadIdx.x;

    // ---- stage weights into LDS ----
    for (int idx=tid; idx<51*40; idx+=NTH){
        int k = idx/40, j = idx - 40*k;
        float4 w;
        if (k < 11){
            w.x=w_ih0[j*11+k]; w.y=w_ih0[(40+j)*11+k]; w.z=w_ih0[(80+j)*11+k]; w.w=w_ih0[(120+j)*11+k];
        } else {
            int kk=k-11;
            w.x=w_hh0[j*40+kk]; w.y=w_hh0[(40+j)*40+kk]; w.z=w_hh0[(80+j)*40+kk]; w.w=w_hh0[(120+j)*40+kk];
        }
        W0[idx]=w;
    }
    for (int idx=tid; idx<80*40; idx+=NTH){
        int k = idx/40, j = idx - 40*k;
        const float* wm = (k<40) ? w_ih1 : w_hh1;
        int kk = (k<40) ? k : k-40;
        float4 w;
        w.x=wm[j*40+kk]; w.y=wm[(40+j)*40+kk]; w.z=wm[(80+j)*40+kk]; w.w=wm[(120+j)*40+kk];
        W1[idx]=w;
    }
    for (int idx=tid; idx<80*21; idx+=NTH){
        int k = idx/21, jo = idx - 21*k;
        int hp = (k<40) ? 2*k : 2*(k-40)+1;   // hp interleave: [h0,h1] pairs
        Wh[k*22+jo] = (jo==0) ? w_gamma[hp] : w_eta[(jo-1)*80 + hp];
    }
    if (tid < 40){
        bc0v[tid] = make_float4(b0[tid], b0[40+tid], b0[80+tid], b0[120+tid]);
        bc1v[tid] = make_float4(b1[tid], b1[40+tid], b1[80+tid], b1[120+tid]);
    }
    if (tid == 0) bh[0] = b_gamma[0];
    if (tid >= 1 && tid < 21) bh[tid] = b_eta[tid-1];
    for (int idx=tid; idx<16*53; idx+=NTH) S0[idx]=0.f;
    for (int idx=tid; idx<16*81; idx+=NTH) S1[idx]=0.f;
    __syncthreads();

    const int j = tid >> 4;        // hidden unit
    const int r = tid & 15;        // row within block
    const int row0 = blockIdx.x * ROWSPB;
    float c0 = 0.f, c1 = 0.f;

    for (int t=0; t<TSTEPS; ++t){
        // phase 1: load feat tile (704B coalesced)
        if (tid < ROWSPB*FCNN){
            S0[(tid/FCNN)*53 + (tid - FCNN*(tid/FCNN))] =
                feat[((size_t)t*BATCH + row0)*FCNN + tid];
        }
        __syncthreads();

        // layer0 matvec: K = 11 feat + 40 h0
        float4 acc = bc0v[j];
        {
            const float* s0r = &S0[r*53];
            #pragma unroll
            for (int k=0; k<51; ++k){
                float4 w = W0[k*40+j];
                float  x = s0r[k];
                acc.x=fmaf(w.x,x,acc.x); acc.y=fmaf(w.y,x,acc.y);
                acc.z=fmaf(w.z,x,acc.z); acc.w=fmaf(w.w,x,acc.w);
            }
        }
        __syncthreads();   // all reads of old h0 done
        {
            float ig=sigm_(acc.x), fg=sigm_(acc.y), gv=tanh_(acc.z), og=sigm_(acc.w);
            c0 = fmaf(fg, c0, ig*gv);
            float h0v = og * tanh_(c0);
            S0[r*53 + 11 + j] = h0v;   // next step's layer0 input
            S1[r*81 + j]      = h0v;   // this step's layer1 input
        }
        __syncthreads();

        // layer1 matvec: K = 40 h0new + 40 h1old
        acc = bc1v[j];
        {
            const float* s1r = &S1[r*81];
            #pragma unroll
            for (int k=0; k<80; ++k){
                float4 w = W1[k*40+j];
                float  x = s1r[k];
                acc.x=fmaf(w.x,x,acc.x); acc.y=fmaf(w.y,x,acc.y);
                acc.z=fmaf(w.z,x,acc.z); acc.w=fmaf(w.w,x,acc.w);
            }
        }
        __syncthreads();   // all reads of old h1 done
        {
            float ig=sigm_(acc.x), fg=sigm_(acc.y), gv=tanh_(acc.z), og=sigm_(acc.w);
            c1 = fmaf(fg, c1, ig*gv);
            float h1v = og * tanh_(c1);
            S1[r*81 + 40 + j] = h1v;
        }
        __syncthreads();

        // heads: 21 outputs, K=80 over S1 (hp interleave folded into Wh)
        if (tid < ROWSPB*NOUT){
            int rr = tid / NOUT, jo = tid - NOUT*rr;
            float a = bh[jo];
            const float* s1r = &S1[rr*81];
            #pragma unroll
            for (int k=0; k<80; ++k) a = fmaf(Wh[k*22+jo], s1r[k], a);
            Sout[tid] = softplus_(a);
        }
        __syncthreads();
        if (tid < ROWSPB*NOUT){
            out[((size_t)t*BATCH + row0)*NOUT + tid] = Sout[tid];  // 1344B coalesced
        }
        // next-iter hazards all separated by the syncs above
    }
}

// ---------------------------------------------------------------------------
extern "C" void kernel_launch(void* const* d_in, const int* in_sizes, int n_in,
                              void* d_out, int out_size, void* d_ws, size_t ws_size,
                              hipStream_t stream)
{
    (void)in_sizes; (void)n_in; (void)out_size; (void)ws_size;
    const float* x_enc   = (const float*)d_in[0];
    const float* y_enc   = (const float*)d_in[3];
    const float* conv_w  = (const float*)d_in[5];
    const float* conv_b  = (const float*)d_in[6];
    const float* bn_w    = (const float*)d_in[7];
    const float* bn_b    = (const float*)d_in[8];
    const float* w_ih0   = (const float*)d_in[9];
    const float* w_hh0   = (const float*)d_in[10];
    const float* b0      = (const float*)d_in[11];
    const float* w_ih1   = (const float*)d_in[12];
    const float* w_hh1   = (const float*)d_in[13];
    const float* b1      = (const float*)d_in[14];
    const float* w_gamma = (const float*)d_in[15];
    const float* b_gamma = (const float*)d_in[16];
    const float* w_eta   = (const float*)d_in[17];
    const float* b_eta   = (const float*)d_in[18];

    float* out   = (float*)d_out;
    float* stats = (float*)d_ws;
    float* feat  = (float*)((char*)d_ws + FEAT_OFF);

    // allow >64KB dynamic LDS on gfx950 (160KB/CU)
    (void)hipFuncSetAttribute((const void*)lstm_kernel,
                              hipFuncAttributeMaxDynamicSharedMemorySize, SMEM_BYTES);

    stats_kernel<<<TSTEPS, 256, 0, stream>>>(x_enc, y_enc, conv_w, conv_b, bn_w, bn_b, stats);
    feat_kernel<<<dim3(TSTEPS, BATCH/256), 256, 0, stream>>>(x_enc, y_enc, conv_w, conv_b, stats, feat);
    lstm_kernel<<<BATCH/ROWSPB, NTH, SMEM_BYTES, stream>>>(feat,
        w_ih0, w_hh0, b0, w_ih1, w_hh1, b1, w_gamma, b_gamma, w_eta, b_eta, out);
}

// Round 3
// 996.282 us; speedup vs baseline: 1.2340x; 1.2340x over previous
//
#include <hip/hip_runtime.h>
#include <cstdint>
#include <cstddef>

// ---------------- problem constants ----------------
#define TSTEPS 192
#define BATCH  4096
#define FRAW   20
#define FCONV  22
#define FCNN   11
#define HID    40
#define NOUT   21          // 1 gamma + 20 eta
#define ROWSPB 16          // rows per LSTM block
#define NTH    640         // 40 units * 16 rows

#define S0STR  68          // floats per S0 row (17 float4, odd -> <=2-way banks)
#define S1STR  84          // floats per S1 row (21 float4, odd -> <=2-way banks)

// ws layout: [0,1536) stats float2 per t ; feat at offset 4096
#define FEAT_OFF 4096

__device__ __forceinline__ float sigm_(float x){ return 1.f/(1.f+__expf(-x)); }
__device__ __forceinline__ float tanh_(float x){ float e=__expf(2.f*x); return 1.f-2.f/(e+1.f); }
__device__ __forceinline__ float softplus_(float x){ return fmaxf(x,0.f)+log1pf(__expf(-fabsf(x))); }

// -------- kernel 1: per-t BN affine params (deterministic block reduce) -----
__global__ __launch_bounds__(256)
void stats_kernel(const float* __restrict__ x_enc, const float* __restrict__ y_enc,
                  const float* __restrict__ conv_w, const float* __restrict__ conv_b,
                  const float* __restrict__ bn_w, const float* __restrict__ bn_b,
                  float* __restrict__ stats)
{
    const int t = blockIdx.x;
    const float w0=conv_w[0], w1=conv_w[1], w2=conv_w[2], cb=conv_b[0];
    const float* src = (t < 96) ? (x_enc + (size_t)t*21) : (y_enc + (size_t)(t-96)*21);
    float s=0.f, ss=0.f;
    for (int b = threadIdx.x; b < BATCH; b += 256) {
        const float* xr = src + (size_t)b*2016;   // 96*21
        float xv[FRAW];
        #pragma unroll
        for (int f=0; f<FRAW; ++f) xv[f] = xr[f];
        #pragma unroll
        for (int i=0; i<FCONV; ++i) {
            float y = fmaf(w0, xv[(i+18)%20], fmaf(w1, xv[(i+19)%20], fmaf(w2, xv[i%20], cb)));
            s += y; ss = fmaf(y, y, ss);
        }
    }
    __shared__ float rs[256], rq[256];
    rs[threadIdx.x]=s; rq[threadIdx.x]=ss;
    __syncthreads();
    for (int o=128; o>0; o>>=1){
        if (threadIdx.x < o){ rs[threadIdx.x]+=rs[threadIdx.x+o]; rq[threadIdx.x]+=rq[threadIdx.x+o]; }
        __syncthreads();
    }
    if (threadIdx.x == 0){
        const float N = (float)(BATCH*FCONV);
        float mu  = rs[0]/N;
        float var = rq[0]/N - mu*mu;
        float A   = rsqrtf(var + 1e-5f) * bn_w[0];
        stats[2*t]   = A;
        stats[2*t+1] = bn_b[0] - mu*A;
    }
}

// -------- kernel 2: conv + BN + ELU + maxpool -> feat[t][b][11] -------------
__global__ __launch_bounds__(256)
void feat_kernel(const float* __restrict__ x_enc, const float* __restrict__ y_enc,
                 const float* __restrict__ conv_w, const float* __restrict__ conv_b,
                 const float* __restrict__ stats, float* __restrict__ feat)
{
    const int t = blockIdx.x;
    const int b = blockIdx.y*256 + threadIdx.x;
    const float w0=conv_w[0], w1=conv_w[1], w2=conv_w[2], cb=conv_b[0];
    const float A = stats[2*t], Bc = stats[2*t+1];
    const float* xr = ((t<96) ? (x_enc + (size_t)t*21) : (y_enc + (size_t)(t-96)*21)) + (size_t)b*2016;
    float xv[FRAW];
    #pragma unroll
    for (int f=0; f<FRAW; ++f) xv[f] = xr[f];
    float yv[FCONV];
    #pragma unroll
    for (int i=0; i<FCONV; ++i) {
        float y = fmaf(w0, xv[(i+18)%20], fmaf(w1, xv[(i+19)%20], fmaf(w2, xv[i%20], cb)));
        y = fmaf(y, A, Bc);
        yv[i] = (y > 0.f) ? y : expm1f(y);
    }
    float* fo = feat + ((size_t)t*BATCH + b)*FCNN;
    #pragma unroll
    for (int i=0; i<FCNN; ++i) {
        float m = (i==0) ? fmaxf(yv[0], yv[1])
                         : fmaxf(yv[2*i-1], fmaxf(yv[2*i], yv[2*i+1]));
        fo[i] = m;
    }
}

// -------- kernel 3: persistent 2-layer LSTM + heads -------------------------
// 256 blocks x 640 threads, 1 block/CU. thread = (j = tid>>4, r = tid&15).
// Double-buffered state, 2 barriers/step, heads overlap next step's layer0.
// LDS layout (bytes):
//   W0   [52][40] float4  @      0  (33280)  k=51 zero-padded
//   W1   [80][40] float4  @  33280  (51200)
//   Wh   [21][84] float   @  84480  (7056)   [jo][k<40: w(2k) | 40+k: w(2k+1)]
//   bc0v [40] float4      @  91536  (640)
//   bc1v [40] float4      @  92176  (640)
//   bh   [21] float       @  92816  (96 incl pad)
//   S0   2x[16][68] float @  92912  (8704)   [0:11)=feat, [11:51)=h0, rest 0
//   S1   2x[16][84] float @ 101616  (10752)  [0:40)=h0new, [40:80)=h1
#define SMEM_BYTES 112384

__global__ __launch_bounds__(NTH, 3)
void lstm_kernel(const float* __restrict__ feat,
                 const float* __restrict__ w_ih0, const float* __restrict__ w_hh0, const float* __restrict__ b0,
                 const float* __restrict__ w_ih1, const float* __restrict__ w_hh1, const float* __restrict__ b1,
                 const float* __restrict__ w_gamma, const float* __restrict__ b_gamma,
                 const float* __restrict__ w_eta,   const float* __restrict__ b_eta,
                 float* __restrict__ out)
{
    extern __shared__ char smem[];
    float4* W0   = (float4*)(smem);
    float4* W1   = (float4*)(smem + 33280);
    float*  Wh   = (float*) (smem + 84480);
    float4* bc0v = (float4*)(smem + 91536);
    float4* bc1v = (float4*)(smem + 92176);
    float*  bh   = (float*) (smem + 92816);
    float*  S0   = (float*) (smem + 92912);
    float*  S1   = (float*) (smem + 101616);

    const int tid  = threadIdx.x;
    const int row0 = blockIdx.x * ROWSPB;

    // ---- stage weights into LDS ----
    for (int idx=tid; idx<52*40; idx+=NTH){
        int k = idx/40, j = idx - 40*k;
        float4 w;
        if (k < 11){
            w.x=w_ih0[j*11+k]; w.y=w_ih0[(40+j)*11+k]; w.z=w_ih0[(80+j)*11+k]; w.w=w_ih0[(120+j)*11+k];
        } else if (k < 51){
            int kk=k-11;
            w.x=w_hh0[j*40+kk]; w.y=w_hh0[(40+j)*40+kk]; w.z=w_hh0[(80+j)*40+kk]; w.w=w_hh0[(120+j)*40+kk];
        } else {
            w = make_float4(0.f,0.f,0.f,0.f);
        }
        W0[idx]=w;
    }
    for (int idx=tid; idx<80*40; idx+=NTH){
        int k = idx/40, j = idx - 40*k;
        const float* wm = (k<40) ? w_ih1 : w_hh1;
        int kk = (k<40) ? k : k-40;
        float4 w;
        w.x=wm[j*40+kk]; w.y=wm[(40+j)*40+kk]; w.z=wm[(80+j)*40+kk]; w.w=wm[(120+j)*40+kk];
        W1[idx]=w;
    }
    for (int idx=tid; idx<21*80; idx+=NTH){
        int jo = idx/80, k = idx - 80*jo;
        int col = (k<40) ? 2*k : 2*(k-40)+1;          // hp interleave folded
        Wh[jo*84 + k] = (jo==0) ? w_gamma[col] : w_eta[(jo-1)*80 + col];
    }
    if (tid < 40){
        bc0v[tid] = make_float4(b0[tid], b0[40+tid], b0[80+tid], b0[120+tid]);
        bc1v[tid] = make_float4(b1[tid], b1[40+tid], b1[80+tid], b1[120+tid]);
    }
    if (tid == 0) bh[0] = b_gamma[0];
    if (tid >= 1 && tid < 21) bh[tid] = b_eta[tid-1];
    for (int idx=tid; idx<2*16*S0STR; idx+=NTH) S0[idx]=0.f;
    for (int idx=tid; idx<2*16*S1STR; idx+=NTH) S1[idx]=0.f;
    __syncthreads();   // <-- zero-init fully visible BEFORE feat(0) staging (fixes the race)
    // prologue: feat(0) into S0 buf 0
    if (tid < ROWSPB*FCNN){
        int rr = tid/11, ff = tid - 11*rr;
        S0[rr*S0STR + ff] = feat[(size_t)row0*FCNN + tid];
    }
    __syncthreads();

    const int j = tid >> 4;
    const int r = tid & 15;
    float c0 = 0.f, c1 = 0.f;
    int p = 0;

    for (int t=0; t<TSTEPS; ++t){
        // prefetch feat(t+1) into registers (overlaps layer0 matvec)
        float fpre = 0.f;
        if (tid < ROWSPB*FCNN && t+1 < TSTEPS)
            fpre = feat[((size_t)(t+1)*BATCH + row0)*FCNN + tid];

        // ---- layer0 matvec: K = 52 (11 feat + 40 h0 + 1 zero pad) ----
        float4 acc = bc0v[j];
        {
            const float4* xv = (const float4*)(S0 + (p*16 + r)*S0STR);
            #pragma unroll
            for (int kk=0; kk<13; ++kk){
                float4 x4 = xv[kk];
                float4 wa = W0[(4*kk+0)*40+j];
                float4 wb = W0[(4*kk+1)*40+j];
                float4 wc = W0[(4*kk+2)*40+j];
                float4 wd = W0[(4*kk+3)*40+j];
                acc.x = fmaf(wa.x,x4.x, fmaf(wb.x,x4.y, fmaf(wc.x,x4.z, fmaf(wd.x,x4.w, acc.x))));
                acc.y = fmaf(wa.y,x4.x, fmaf(wb.y,x4.y, fmaf(wc.y,x4.z, fmaf(wd.y,x4.w, acc.y))));
                acc.z = fmaf(wa.z,x4.x, fmaf(wb.z,x4.y, fmaf(wc.z,x4.z, fmaf(wd.z,x4.w, acc.z))));
                acc.w = fmaf(wa.w,x4.x, fmaf(wb.w,x4.y, fmaf(wc.w,x4.z, fmaf(wd.w,x4.w, acc.w))));
            }
        }
        {
            float ig=sigm_(acc.x), fg=sigm_(acc.y), gv=tanh_(acc.z), og=sigm_(acc.w);
            c0 = fmaf(fg, c0, ig*gv);
            float h0v = og * tanh_(c0);
            S0[((p^1)*16 + r)*S0STR + 11 + j] = h0v;   // next step's layer0 input
            S1[(p*16 + r)*S1STR + j]          = h0v;   // this step's layer1 input
        }
        __syncthreads();   // B1: h0(t) visible

        // ---- layer1 matvec: K = 80 (40 h0new + 40 h1old) ----
        acc = bc1v[j];
        {
            const float4* yv = (const float4*)(S1 + (p*16 + r)*S1STR);
            #pragma unroll
            for (int kk=0; kk<20; ++kk){
                float4 x4 = yv[kk];
                float4 wa = W1[(4*kk+0)*40+j];
                float4 wb = W1[(4*kk+1)*40+j];
                float4 wc = W1[(4*kk+2)*40+j];
                float4 wd = W1[(4*kk+3)*40+j];
                acc.x = fmaf(wa.x,x4.x, fmaf(wb.x,x4.y, fmaf(wc.x,x4.z, fmaf(wd.x,x4.w, acc.x))));
                acc.y = fmaf(wa.y,x4.x, fmaf(wb.y,x4.y, fmaf(wc.y,x4.z, fmaf(wd.y,x4.w, acc.y))));
                acc.z = fmaf(wa.z,x4.x, fmaf(wb.z,x4.y, fmaf(wc.z,x4.z, fmaf(wd.z,x4.w, acc.z))));
                acc.w = fmaf(wa.w,x4.x, fmaf(wb.w,x4.y, fmaf(wc.w,x4.z, fmaf(wd.w,x4.w, acc.w))));
            }
        }
        {
            float ig=sigm_(acc.x), fg=sigm_(acc.y), gv=tanh_(acc.z), og=sigm_(acc.w);
            c1 = fmaf(fg, c1, ig*gv);
            float h1v = og * tanh_(c1);
            S1[((p^1)*16 + r)*S1STR + 40 + j] = h1v;
        }
        if (tid < ROWSPB*FCNN && t+1 < TSTEPS){
            int rr = tid/11, ff = tid - 11*rr;
            S0[((p^1)*16 + rr)*S0STR + ff] = fpre;     // feat(t+1)
        }
        __syncthreads();   // B2: h1(t) + feat(t+1) visible

        // ---- heads: overlap with next step's layer0 (no barrier after) ----
        // Safe: reads S1[p][0:40) and S1[p^1][40:80); the only concurrent
        // writes (next iter's phase A) touch S1[p^1][0:40) and S0[p][11:51).
        if (tid < ROWSPB*NOUT){
            int rr = tid/21, jo = tid - 21*rr;
            const float4* h0p = (const float4*)(S1 + (p*16 + rr)*S1STR);
            const float4* h1p = (const float4*)(S1 + ((p^1)*16 + rr)*S1STR + 40);
            const float4* whp = (const float4*)(Wh + jo*84);
            float sa=0.f, sb=0.f, sc=0.f, sd=0.f;
            #pragma unroll
            for (int kk=0; kk<10; ++kk){
                float4 x4 = h0p[kk]; float4 w4 = whp[kk];
                sa=fmaf(w4.x,x4.x,sa); sb=fmaf(w4.y,x4.y,sb);
                sc=fmaf(w4.z,x4.z,sc); sd=fmaf(w4.w,x4.w,sd);
            }
            #pragma unroll
            for (int kk=0; kk<10; ++kk){
                float4 x4 = h1p[kk]; float4 w4 = whp[10+kk];
                sa=fmaf(w4.x,x4.x,sa); sb=fmaf(w4.y,x4.y,sb);
                sc=fmaf(w4.z,x4.z,sc); sd=fmaf(w4.w,x4.w,sd);
            }
            float a = bh[jo] + ((sa+sb)+(sc+sd));
            out[((size_t)t*BATCH + row0)*NOUT + tid] = softplus_(a);
        }
        p ^= 1;
    }
}

// ---------------------------------------------------------------------------
extern "C" void kernel_launch(void* const* d_in, const int* in_sizes, int n_in,
                              void* d_out, int out_size, void* d_ws, size_t ws_size,
                              hipStream_t stream)
{
    (void)in_sizes; (void)n_in; (void)out_size; (void)ws_size;
    const float* x_enc   = (const float*)d_in[0];
    const float* y_enc   = (const float*)d_in[3];
    const float* conv_w  = (const float*)d_in[5];
    const float* conv_b  = (const float*)d_in[6];
    const float* bn_w    = (const float*)d_in[7];
    const float* bn_b    = (const float*)d_in[8];
    const float* w_ih0   = (const float*)d_in[9];
    const float* w_hh0   = (const float*)d_in[10];
    const float* b0      = (const float*)d_in[11];
    const float* w_ih1   = (const float*)d_in[12];
    const float* w_hh1   = (const float*)d_in[13];
    const float* b1      = (const float*)d_in[14];
    const float* w_gamma = (const float*)d_in[15];
    const float* b_gamma = (const float*)d_in[16];
    const float* w_eta   = (const float*)d_in[17];
    const float* b_eta   = (const float*)d_in[18];

    float* out   = (float*)d_out;
    float* stats = (float*)d_ws;
    float* feat  = (float*)((char*)d_ws + FEAT_OFF);

    (void)hipFuncSetAttribute((const void*)lstm_kernel,
                              hipFuncAttributeMaxDynamicSharedMemorySize, SMEM_BYTES);

    stats_kernel<<<TSTEPS, 256, 0, stream>>>(x_enc, y_enc, conv_w, conv_b, bn_w, bn_b, stats);
    feat_kernel<<<dim3(TSTEPS, BATCH/256), 256, 0, stream>>>(x_enc, y_enc, conv_w, conv_b, stats, feat);
    lstm_kernel<<<BATCH/ROWSPB, NTH, SMEM_BYTES, stream>>>(feat,
        w_ih0, w_hh0, b0, w_ih1, w_hh1, b1, w_gamma, b_gamma, w_eta, b_eta, out);
}

// Round 4
// 531.221 us; speedup vs baseline: 2.3143x; 1.8755x over previous
//
#include <hip/hip_runtime.h>
#include <cstdint>
#include <cstddef>

// ---------------- problem constants ----------------
#define TSTEPS 192
#define BATCH  4096
#define FRAW   20
#define FCONV  22
#define FCNN   11
#define HID    40
#define NOUT   21
#define ROWSPB 16
#define NTH    640          // 10 waves: wave w owns gate-tile w (units 4w..4w+3)

#define FEAT_OFF 4096       // ws: [0,1536) stats ; feat at byte offset 4096

typedef _Float16 half8 __attribute__((ext_vector_type(8)));
typedef float    f32x4 __attribute__((ext_vector_type(4)));
#define MFMA16(a,b,c) __builtin_amdgcn_mfma_f32_16x16x32_f16(a,b,c,0,0,0)

__device__ __forceinline__ float sigm_(float x){ return 1.f/(1.f+__expf(-x)); }
__device__ __forceinline__ float tanh_(float x){ float e=__expf(2.f*x); return 1.f-2.f/(e+1.f); }
__device__ __forceinline__ float softplus_(float x){ return fmaxf(x,0.f)+log1pf(__expf(-fabsf(x))); }

// -------- kernel 1: per-t BN affine params (unchanged) ----------------------
__global__ __launch_bounds__(256)
void stats_kernel(const float* __restrict__ x_enc, const float* __restrict__ y_enc,
                  const float* __restrict__ conv_w, const float* __restrict__ conv_b,
                  const float* __restrict__ bn_w, const float* __restrict__ bn_b,
                  float* __restrict__ stats)
{
    const int t = blockIdx.x;
    const float w0=conv_w[0], w1=conv_w[1], w2=conv_w[2], cb=conv_b[0];
    const float* src = (t < 96) ? (x_enc + (size_t)t*21) : (y_enc + (size_t)(t-96)*21);
    float s=0.f, ss=0.f;
    for (int b = threadIdx.x; b < BATCH; b += 256) {
        const float* xr = src + (size_t)b*2016;
        float xv[FRAW];
        #pragma unroll
        for (int f=0; f<FRAW; ++f) xv[f] = xr[f];
        #pragma unroll
        for (int i=0; i<FCONV; ++i) {
            float y = fmaf(w0, xv[(i+18)%20], fmaf(w1, xv[(i+19)%20], fmaf(w2, xv[i%20], cb)));
            s += y; ss = fmaf(y, y, ss);
        }
    }
    __shared__ float rs[256], rq[256];
    rs[threadIdx.x]=s; rq[threadIdx.x]=ss;
    __syncthreads();
    for (int o=128; o>0; o>>=1){
        if (threadIdx.x < o){ rs[threadIdx.x]+=rs[threadIdx.x+o]; rq[threadIdx.x]+=rq[threadIdx.x+o]; }
        __syncthreads();
    }
    if (threadIdx.x == 0){
        const float N = (float)(BATCH*FCONV);
        float mu  = rs[0]/N;
        float var = rq[0]/N - mu*mu;
        float A   = rsqrtf(var + 1e-5f) * bn_w[0];
        stats[2*t]   = A;
        stats[2*t+1] = bn_b[0] - mu*A;
    }
}

// -------- kernel 2: conv + BN + ELU + maxpool (unchanged) -------------------
__global__ __launch_bounds__(256)
void feat_kernel(const float* __restrict__ x_enc, const float* __restrict__ y_enc,
                 const float* __restrict__ conv_w, const float* __restrict__ conv_b,
                 const float* __restrict__ stats, float* __restrict__ feat)
{
    const int t = blockIdx.x;
    const int b = blockIdx.y*256 + threadIdx.x;
    const float w0=conv_w[0], w1=conv_w[1], w2=conv_w[2], cb=conv_b[0];
    const float A = stats[2*t], Bc = stats[2*t+1];
    const float* xr = ((t<96) ? (x_enc + (size_t)t*21) : (y_enc + (size_t)(t-96)*21)) + (size_t)b*2016;
    float xv[FRAW];
    #pragma unroll
    for (int f=0; f<FRAW; ++f) xv[f] = xr[f];
    float yv[FCONV];
    #pragma unroll
    for (int i=0; i<FCONV; ++i) {
        float y = fmaf(w0, xv[(i+18)%20], fmaf(w1, xv[(i+19)%20], fmaf(w2, xv[i%20], cb)));
        y = fmaf(y, A, Bc);
        yv[i] = (y > 0.f) ? y : expm1f(y);
    }
    float* fo = feat + ((size_t)t*BATCH + b)*FCNN;
    #pragma unroll
    for (int i=0; i<FCNN; ++i) {
        float m = (i==0) ? fmaxf(yv[0], yv[1])
                         : fmaxf(yv[2*i-1], fmaxf(yv[2*i], yv[2*i+1]));
        fo[i] = m;
    }
}

// -------- kernel 3: persistent MFMA LSTM ------------------------------------
// 256 blocks x 640 thr (10 waves), 1 block/CU, 16 rows/block.
// W in registers as fp16 hi/lo fragments (gate rows unit-major so the 4
// gates of unit u land in one lane's 4 acc regs). x/h staged in LDS as
// fp16 hi/lo, k-contiguous -> B-frags are raw ds_read_b128.
// LDS (static, 24.6 KB):
//   B0{h,l}[2][16][88] : k<11 feat | 11..51 h0 | 51..64 zero (stride 88: 16B-align + 2-way banks)
//   B1{h,l}[2][16][104]: k<40 h0new | 40..80 h1 | 80..96 zero
__global__ __launch_bounds__(NTH, 3)
void lstm_kernel(const float* __restrict__ feat,
                 const float* __restrict__ w_ih0, const float* __restrict__ w_hh0, const float* __restrict__ b0,
                 const float* __restrict__ w_ih1, const float* __restrict__ w_hh1, const float* __restrict__ b1,
                 const float* __restrict__ w_gamma, const float* __restrict__ b_gamma,
                 const float* __restrict__ w_eta,   const float* __restrict__ b_eta,
                 float* __restrict__ out)
{
    __shared__ __align__(16) _Float16 B0h[2][16][88];
    __shared__ __align__(16) _Float16 B0l[2][16][88];
    __shared__ __align__(16) _Float16 B1h[2][16][104];
    __shared__ __align__(16) _Float16 B1l[2][16][104];

    const int tid  = threadIdx.x;
    const int row0 = blockIdx.x * ROWSPB;
    const int l    = tid & 63;
    const int wv   = tid >> 6;      // wave = gate tile 0..9
    const int q    = l >> 4;        // k-chunk / D-row group
    const int mr   = l & 15;        // A-row within tile, B col = batch row, D col

    // ---- zero LDS ----
    {
        uint32_t* z;
        z = (uint32_t*)&B0h[0][0][0]; for (int i=tid;i<1408;i+=NTH) z[i]=0u;
        z = (uint32_t*)&B0l[0][0][0]; for (int i=tid;i<1408;i+=NTH) z[i]=0u;
        z = (uint32_t*)&B1h[0][0][0]; for (int i=tid;i<1664;i+=NTH) z[i]=0u;
        z = (uint32_t*)&B1l[0][0][0]; for (int i=tid;i<1664;i+=NTH) z[i]=0u;
    }

    // ---- A fragments (one-time). Global gate row for A-load lane:
    // tile row m=mr -> unit 4wv + (mr>>2), gate mr&3 -> torch row gate*40+unit.
    const int uA = 4*wv + (mr >> 2);
    const int RA = (mr & 3)*40 + uA;
    half8 a0h[2], a0l[2], a1h[3], a1l[3], ahd[3];
    #pragma unroll
    for (int f=0; f<2; ++f){
        #pragma unroll
        for (int i=0; i<8; ++i){
            int k = f*32 + q*8 + i;
            float v = (k<11) ? w_ih0[RA*11 + k] : ((k<51) ? w_hh0[RA*40 + k - 11] : 0.f);
            _Float16 h = (_Float16)v;
            a0h[f][i] = h; a0l[f][i] = (_Float16)(v - (float)h);
        }
    }
    #pragma unroll
    for (int f=0; f<3; ++f){
        #pragma unroll
        for (int i=0; i<8; ++i){
            int k = f*32 + q*8 + i;
            float v = (k<40) ? w_ih1[RA*40 + k] : ((k<80) ? w_hh1[RA*40 + k - 40] : 0.f);
            _Float16 h = (_Float16)v;
            a1h[f][i] = h; a1l[f][i] = (_Float16)(v - (float)h);
        }
    }
    {
        int jo = 16*wv + mr;    // head A row (valid wv<2, jo<21)
        #pragma unroll
        for (int f=0; f<3; ++f){
            #pragma unroll
            for (int i=0; i<8; ++i){
                int k = f*32 + q*8 + i;
                float v = 0.f;
                if (wv < 2 && jo < NOUT && k < 80){
                    int col = (k<40) ? 2*k : 2*(k-40)+1;   // hp interleave folded
                    v = (jo==0) ? w_gamma[col] : w_eta[(jo-1)*80 + col];
                }
                ahd[f][i] = (_Float16)v;
            }
        }
    }

    // ---- biases (per-lane, unit uG = 4wv+q owns gates i,f,g,o = regs 0..3)
    const int uG = 4*wv + q;
    f32x4 bias0, bias1, biash;
    bias0[0]=b0[uG]; bias0[1]=b0[40+uG]; bias0[2]=b0[80+uG]; bias0[3]=b0[120+uG];
    bias1[0]=b1[uG]; bias1[1]=b1[40+uG]; bias1[2]=b1[80+uG]; bias1[3]=b1[120+uG];
    #pragma unroll
    for (int e=0; e<4; ++e){
        int jo = 16*wv + 4*q + e;
        biash[e] = (wv < 2 && jo < NOUT) ? ((jo==0) ? b_gamma[0] : b_eta[jo-1]) : 0.f;
    }

    // ---- feat staging threads: waves 7-9 (tid >= 464), 176 = 16 rows x 11
    const int  ft     = tid - 464;
    const bool isFeat = (ft >= 0 && ft < ROWSPB*FCNN);
    const int  frr    = isFeat ? (ft / FCNN) : 0;
    const int  fff    = isFeat ? (ft - FCNN*frr) : 0;

    __syncthreads();   // zero-init visible before feat(0) staging
    if (isFeat){
        float v = feat[(size_t)(row0 + frr)*FCNN + fff];   // t = 0
        _Float16 h = (_Float16)v;
        B0h[0][frr][fff] = h; B0l[0][frr][fff] = (_Float16)(v - (float)h);
    }
    __syncthreads();

    float c0 = 0.f, c1 = 0.f;
    int p = 0;
    for (int t=0; t<TSTEPS; ++t){
        // global prefetch of feat(t+1), consumed in phase 2
        float fpre = 0.f;
        if (isFeat && t+1 < TSTEPS)
            fpre = feat[((size_t)(t+1)*BATCH + row0 + frr)*FCNN + fff];

        // ---- phase 1: layer0  (K = 64: feat|h0|pad), triple hi/lo product
        f32x4 acc = bias0;
        {
            const _Float16* rh = &B0h[p][mr][0];
            const _Float16* rl = &B0l[p][mr][0];
            half8 xh0 = *(const half8*)(rh + q*8);
            half8 xl0 = *(const half8*)(rl + q*8);
            half8 xh1 = *(const half8*)(rh + 32 + q*8);
            half8 xl1 = *(const half8*)(rl + 32 + q*8);
            acc = MFMA16(a0h[0], xh0, acc);
            acc = MFMA16(a0h[0], xl0, acc);
            acc = MFMA16(a0l[0], xh0, acc);
            acc = MFMA16(a0h[1], xh1, acc);
            acc = MFMA16(a0h[1], xl1, acc);
            acc = MFMA16(a0l[1], xh1, acc);
        }
        {
            float ig=sigm_(acc[0]), fg=sigm_(acc[1]), gv=tanh_(acc[2]), og=sigm_(acc[3]);
            c0 = fmaf(fg, c0, ig*gv);
            float h0v = og * tanh_(c0);
            _Float16 hh = (_Float16)h0v, hl = (_Float16)(h0v - (float)hh);
            B0h[p^1][mr][11+uG] = hh;  B0l[p^1][mr][11+uG] = hl;   // next L0 input
            B1h[p  ][mr][uG]    = hh;  B1l[p  ][mr][uG]    = hl;   // this L1 input
        }
        __syncthreads();   // B1: h0(t) visible in B1[p]

        // ---- phase 2: layer1  (K = 96: h0new|h1old|pad)
        f32x4 acc1 = bias1;
        {
            const _Float16* rh = &B1h[p][mr][0];
            const _Float16* rl = &B1l[p][mr][0];
            #pragma unroll
            for (int f=0; f<3; ++f){
                half8 xh = *(const half8*)(rh + f*32 + q*8);
                half8 xl = *(const half8*)(rl + f*32 + q*8);
                acc1 = MFMA16(a1h[f], xh, acc1);
                acc1 = MFMA16(a1h[f], xl, acc1);
                acc1 = MFMA16(a1l[f], xh, acc1);
            }
        }
        {
            float ig=sigm_(acc1[0]), fg=sigm_(acc1[1]), gv=tanh_(acc1[2]), og=sigm_(acc1[3]);
            c1 = fmaf(fg, c1, ig*gv);
            float h1v = og * tanh_(c1);
            _Float16 hh = (_Float16)h1v, hl = (_Float16)(h1v - (float)hh);
            B1h[p^1][mr][40+uG] = hh;  B1l[p^1][mr][40+uG] = hl;   // next L1 input + head h1
        }
        if (isFeat && t+1 < TSTEPS){
            _Float16 h = (_Float16)fpre;
            B0h[p^1][frr][fff] = h;  B0l[p^1][frr][fff] = (_Float16)(fpre - (float)h);
        }
        __syncthreads();   // B2: h1(t) + feat(t+1) visible

        // ---- phase 3: heads (waves 0,1) — overlaps next step's phase 1.
        // B = [h0(t) (B1[p][0:40)) | h1(t) (B1[p^1][40:80)) | pad]. Frag1 is
        // per-lane split: q==0 reads k32..39 from B1[p], q>=1 k40..63 from B1[p^1].
        // Safe vs next phase1: it writes B1[p^1][k<40) and B0 only.
        if (wv < 2){
            f32x4 ah = biash;
            const _Float16* rhp  = &B1h[p  ][mr][0];
            const _Float16* rlp  = &B1l[p  ][mr][0];
            const _Float16* rhp1 = &B1h[p^1][mr][0];
            const _Float16* rlp1 = &B1l[p^1][mr][0];
            half8 xh = *(const half8*)(rhp + q*8);
            half8 xl = *(const half8*)(rlp + q*8);
            ah = MFMA16(ahd[0], xh, ah);
            ah = MFMA16(ahd[0], xl, ah);
            const _Float16* sh = (q==0) ? rhp : rhp1;
            const _Float16* sl = (q==0) ? rlp : rlp1;
            xh = *(const half8*)(sh + 32 + q*8);
            xl = *(const half8*)(sl + 32 + q*8);
            ah = MFMA16(ahd[1], xh, ah);
            ah = MFMA16(ahd[1], xl, ah);
            xh = *(const half8*)(rhp1 + 64 + q*8);   // k>=80 region stays zero
            xl = *(const half8*)(rlp1 + 64 + q*8);
            ah = MFMA16(ahd[2], xh, ah);
            ah = MFMA16(ahd[2], xl, ah);
            float* op = out + ((size_t)t*BATCH + row0 + mr)*NOUT;
            #pragma unroll
            for (int e=0; e<4; ++e){
                int jo = 16*wv + 4*q + e;
                if (jo < NOUT) op[jo] = softplus_(ah[e]);
            }
        }
        p ^= 1;
    }
}

// ---------------------------------------------------------------------------
extern "C" void kernel_launch(void* const* d_in, const int* in_sizes, int n_in,
                              void* d_out, int out_size, void* d_ws, size_t ws_size,
                              hipStream_t stream)
{
    (void)in_sizes; (void)n_in; (void)out_size; (void)ws_size;
    const float* x_enc   = (const float*)d_in[0];
    const float* y_enc   = (const float*)d_in[3];
    const float* conv_w  = (const float*)d_in[5];
    const float* conv_b  = (const float*)d_in[6];
    const float* bn_w    = (const float*)d_in[7];
    const float* bn_b    = (const float*)d_in[8];
    const float* w_ih0   = (const float*)d_in[9];
    const float* w_hh0   = (const float*)d_in[10];
    const float* b0      = (const float*)d_in[11];
    const float* w_ih1   = (const float*)d_in[12];
    const float* w_hh1   = (const float*)d_in[13];
    const float* b1      = (const float*)d_in[14];
    const float* w_gamma = (const float*)d_in[15];
    const float* b_gamma = (const float*)d_in[16];
    const float* w_eta   = (const float*)d_in[17];
    const float* b_eta   = (const float*)d_in[18];

    float* out   = (float*)d_out;
    float* stats = (float*)d_ws;
    float* feat  = (float*)((char*)d_ws + FEAT_OFF);

    stats_kernel<<<TSTEPS, 256, 0, stream>>>(x_enc, y_enc, conv_w, conv_b, bn_w, bn_b, stats);
    feat_kernel<<<dim3(TSTEPS, BATCH/256), 256, 0, stream>>>(x_enc, y_enc, conv_w, conv_b, stats, feat);
    lstm_kernel<<<BATCH/ROWSPB, NTH, 0, stream>>>(feat,
        w_ih0, w_hh0, b0, w_ih1, w_hh1, b1, w_gamma, b_gamma, w_eta, b_eta, out);
}